// Round 10
// baseline (97.134 us; speedup 1.0000x reference)
//
#include <hip/hip_runtime.h>
#include <hip/hip_bf16.h>

#define IN_CNT 64
#define FEAT   1024
#define BATCH  256

#define BM 256
#define BN 256
#define BK 32
#define KT (FEAT / BK)   // 32 K-tiles

typedef __attribute__((ext_vector_type(4))) float f32x4;
typedef __attribute__((ext_vector_type(8))) short bf16x8;   // 8 bf16 = one MFMA A/B frag

__device__ __forceinline__ short f2bf(float f) {
    __hip_bfloat16 h = __float2bfloat16(f);
    return __builtin_bit_cast(short, h);
}

__device__ __forceinline__ bf16x8 pack8(f32x4 a, f32x4 b) {
    bf16x8 v;
    v[0] = f2bf(a[0]); v[1] = f2bf(a[1]); v[2] = f2bf(a[2]); v[3] = f2bf(a[3]);
    v[4] = f2bf(b[0]); v[5] = f2bf(b[1]); v[6] = f2bf(b[2]); v[7] = f2bf(b[3]);
    return v;
}

// barrier + LDS drain only; vmcnt managed manually (counted, never 0 mid-loop)
__device__ __forceinline__ void barrier_lgkm() {
    asm volatile("s_waitcnt lgkmcnt(0)" ::: "memory");
    __builtin_amdgcn_s_barrier();
    asm volatile("" ::: "memory");
}

// async global->LDS DMA, 16B per lane. LDS dest = wave-uniform base + lane*16.
__device__ __forceinline__ void gload16(const float* g, float* l) {
    __builtin_amdgcn_global_load_lds(
        (const __attribute__((address_space(1))) void*)g,
        (__attribute__((address_space(3))) void*)l, 16, 0, 0);
}

// 16 waves/CU occupancy experiment: R6 structure at 1024 threads.
__global__ __launch_bounds__(1024, 1)
void split_linear_kernel(const float* __restrict__ x,
                         const float* __restrict__ W,
                         float* __restrict__ out)
{
    // fp32 tiles in LDS: 2 bufs x (A 256x32 = 32KB + B 32KB) = 128 KB.
    // Row = 32 floats = 128 B, 8 granules of 16 B. LDS slot s of row r holds
    // global granule s ^ (r&7) (swizzle applied on DMA source; DMA writes linear).
    __shared__ __align__(16) float lds[32768];

    const int tid = threadIdx.x;

    // bijective XCD swizzle (256 % 8 == 0): the 4 same-gi blocks share one XCD L2.
    const int bid = blockIdx.x;
    const int swz = ((bid & 7) << 5) | (bid >> 3);
    const int gi   = swz >> 2;            // 0..63
    const int ncol = (swz & 3) << 8;      // 0/256/512/768

    const int lane = tid & 63;
    const int wid  = tid >> 6;            // 0..15
    const int wm   = wid >> 2;            // 0..3
    const int wn   = wid & 3;             // 0..3
    const int lr   = lane & 15;
    const int lh   = lane >> 4;

    // ---- DMA source coords: chunk = 8 rows x 8 granules; lane L -> row L>>3,
    // fetches granule (L&7)^(L>>3) so LDS slot (L&7) holds the swizzled granule.
    const int lrow = lane >> 3;                 // 0..7
    const int lgr  = (lane & 7) ^ lrow;         // pre-swizzled source granule
    const float* Asrc = x + ((size_t)lrow * IN_CNT + gi) * FEAT + lgr * 4;
    const float* Bsrc = W + ((size_t)gi * FEAT + ncol + lrow) * FEAT + lgr * 4;

    f32x4 acc[4][4];
#pragma unroll
    for (int m = 0; m < 4; ++m)
#pragma unroll
        for (int n = 0; n < 4; ++n)
            acc[m][n] = (f32x4){0.f, 0.f, 0.f, 0.f};

    // issue one tile's DMA: 64 chunks over 16 waves -> 2 B + 2 A per wave.
    // W (cold, long pole) first.
    auto ISSUE = [&](int kt, int b) {
        float* base = lds + b * 16384;
        const float* a0 = Asrc + (size_t)kt * BK;
        const float* b0 = Bsrc + (size_t)kt * BK;
#pragma unroll
        for (int i = 0; i < 2; ++i) {
            const int c = wid * 2 + i;          // chunk 0..31 (8 rows each)
            gload16(b0 + (size_t)c * (8 * FEAT),          base + 8192 + c * 256);
        }
#pragma unroll
        for (int i = 0; i < 2; ++i) {
            const int c = wid * 2 + i;
            gload16(a0 + (size_t)c * (8 * IN_CNT * FEAT), base + c * 256);
        }
    };

    // read fp32 frag (k = lh*8 .. lh*8+7) from swizzled LDS row, cvt to bf16
    const int sl0 = ((2 * lh)     ^ (lr & 7)) << 2;   // float offsets of the 2 slots
    const int sl1 = ((2 * lh + 1) ^ (lr & 7)) << 2;

    auto COMPUTE = [&](int b) {
        const float* bufA = lds + b * 16384;
        const float* bufB = bufA + 8192;
        bf16x8 bfr[4];
#pragma unroll
        for (int nf = 0; nf < 4; ++nf) {
            const float* rp = bufB + (wn * 64 + nf * 16 + lr) * 32;
            bfr[nf] = pack8(*(const f32x4*)(rp + sl0), *(const f32x4*)(rp + sl1));
        }
        __builtin_amdgcn_s_setprio(1);
#pragma unroll
        for (int mf = 0; mf < 4; ++mf) {
            const float* rp = bufA + (wm * 64 + mf * 16 + lr) * 32;
            bf16x8 af = pack8(*(const f32x4*)(rp + sl0), *(const f32x4*)(rp + sl1));
#pragma unroll
            for (int nf = 0; nf < 4; ++nf)
                acc[mf][nf] = __builtin_amdgcn_mfma_f32_16x16x32_bf16(
                    af, bfr[nf], acc[mf][nf], 0, 0, 0);
        }
        __builtin_amdgcn_s_setprio(0);
    };

    // ---- prologue: tiles 0,1 in flight; wait tile 0 (4 newest stay in flight)
    ISSUE(0, 0);
    ISSUE(1, 1);
    asm volatile("s_waitcnt vmcnt(4)" ::: "memory");
    __builtin_amdgcn_s_barrier();
    asm volatile("" ::: "memory");

    // ---- main loop: compute k | barrier | issue k+2 into k's buf, wait k+1 | barrier
    for (int k = 0; k < KT; ++k) {
        const int b = k & 1;
        COMPUTE(b);
        barrier_lgkm();                        // all waves done reading buf b
        if (k + 2 < KT) {
            ISSUE(k + 2, b);
            asm volatile("s_waitcnt vmcnt(4)" ::: "memory");   // tile k+1 landed
        } else {
            asm volatile("s_waitcnt vmcnt(0)" ::: "memory");   // tail drain
        }
        __builtin_amdgcn_s_barrier();
        asm volatile("" ::: "memory");
    }

    // ---- epilogue: stripe-transpose through LDS -> contiguous f32x4 stores.
    // C/D frag layout: col = lane&15 (n), row = lh*4 + j (m)  [m89-verified]
#define ELD 260
    float* elds = lds;   // 64 rows x 260 floats = 66.6 KB scratch (have 128 KB)
#pragma unroll
    for (int s = 0; s < 4; ++s) {               // 4 stripes of 64 m-rows
        barrier_lgkm();                          // previous stripe fully read
        if (wm == s) {
#pragma unroll
            for (int mf = 0; mf < 4; ++mf)
#pragma unroll
                for (int nf = 0; nf < 4; ++nf)
#pragma unroll
                    for (int j = 0; j < 4; ++j)
                        elds[(mf * 16 + lh * 4 + j) * ELD + wn * 64 + nf * 16 + lr]
                            = acc[mf][nf][j];
        }
        barrier_lgkm();
#pragma unroll
        for (int rr = 0; rr < 4; ++rr) {         // wave w stores rows w*4..w*4+3
            const int rowl = wid * 4 + rr;
            f32x4 v = *(const f32x4*)&elds[rowl * ELD + lane * 4];
            const int m = s * 64 + rowl;
            *(f32x4*)&out[((size_t)m * IN_CNT + gi) * FEAT + ncol + lane * 4] = v;
        }
    }
#undef ELD
}

extern "C" void kernel_launch(void* const* d_in, const int* in_sizes, int n_in,
                              void* d_out, int out_size, void* d_ws, size_t ws_size,
                              hipStream_t stream) {
    const float* x   = (const float*)d_in[0];
    const float* W   = (const float*)d_in[1];
    float*       out = (float*)d_out;

    dim3 grid(IN_CNT * (FEAT / BN));   // 256 blocks: one 256x256 tile each
    dim3 block(1024);
    hipLaunchKernelGGL(split_linear_kernel, grid, block, 0, stream, x, W, out);
}